// Round 2
// baseline (1137.895 us; speedup 1.0000x reference)
//
#include <hip/hip_runtime.h>
#include <hip/hip_bf16.h>

#define NPTS 32768
#define NSLAB 16
#define NF 128
#define HDIM 128
#define PTS_PER_BLK 64

// ---- workspace layout (bytes) ----
// [0, 64)           : g_count[16] (int)
// [1024, 1024+1MB)  : lists, u16 [16][NPTS]
// [2MB, 4MB)        : tau_all, f32 [16][NPTS]
#define WS_COUNT_OFF   0
#define WS_LIST_OFF    1024
#define WS_TAU_OFF     (2u << 20)

__device__ __forceinline__ float fast_tanh(float v) {
    v = fminf(fmaxf(v, -15.0f), 15.0f);
    float t = __builtin_amdgcn_exp2f(v * 2.8853900817779268f); // e^{2v}
    return (t - 1.0f) * __builtin_amdgcn_rcpf(t + 1.0f);
}

__global__ void build_lists(const float* __restrict__ x,
                            const float* __restrict__ mids,
                            const float* __restrict__ widths,
                            int* __restrict__ g_count,
                            unsigned short* __restrict__ lists) {
    __shared__ int cnt[NSLAB];
    __shared__ int base[NSLAB];
    int tid = threadIdx.x;
    if (tid < NSLAB) cnt[tid] = 0;
    __syncthreads();
    int n = blockIdx.x * 256 + tid;
    float xc = x[n * 6];
    int ofs[NSLAB];
    unsigned int amask = 0;
    #pragma unroll
    for (int s = 0; s < NSLAB; ++s) {
        float xmin = mids[s] - 0.5f * widths[s];
        float xmax = mids[s] + 0.5f * widths[s];
        if (xc >= xmin && xc <= xmax) {
            ofs[s] = atomicAdd(&cnt[s], 1);
            amask |= (1u << s);
        }
    }
    __syncthreads();
    if (tid < NSLAB) base[tid] = atomicAdd(&g_count[tid], cnt[tid]);
    __syncthreads();
    #pragma unroll
    for (int s = 0; s < NSLAB; ++s)
        if (amask & (1u << s))
            lists[s * NPTS + base[s] + ofs[s]] = (unsigned short)n;
}

// Block: 256 threads = 4 waves. 64 points (one per lane), one slab.
// Wave w owns output columns [32w, 32w+32). Per-thread state: acc[32].
__global__ __launch_bounds__(256) void mlp_eval(
        const float* __restrict__ x,  const float* __restrict__ B,
        const float* __restrict__ W1, const float* __restrict__ b1,
        const float* __restrict__ W2, const float* __restrict__ b2,
        const float* __restrict__ W3, const float* __restrict__ b3,
        const float* __restrict__ mids, const float* __restrict__ widths,
        const int* __restrict__ g_count,
        const unsigned short* __restrict__ lists,
        float* __restrict__ tau_all) {
    int s = blockIdx.y;
    int count = g_count[s];
    int base = blockIdx.x * PTS_PER_BLK;
    if (count == 0 || base >= count) return;

    int w = threadIdx.x >> 6;   // wave id: column block
    int p = threadIdx.x & 63;   // lane: point
    int idx = base + p;
    bool valid = idx < count;
    int ii = valid ? idx : (count - 1);
    int n = lists[s * NPTS + ii];

    __shared__ float lds_h[HDIM][PTS_PER_BLK];   // h transposed: [col][point]
    __shared__ float lds_r[4][PTS_PER_BLK];

    float mid = mids[s], wd = widths[s];
    float xv[6];
    const float* xr = x + n * 6;
    #pragma unroll
    for (int d = 0; d < 6; ++d) xv[d] = (xr[d] - mid) / wd;

    const float* Bs  = B  + s * (NF * 3);
    const float* W1s = W1 + s * (4 * NF * HDIM);
    const float* b1s = b1 + s * HDIM;
    int colbase = w * 32;

    float acc[32];
    #pragma unroll
    for (int m = 0; m < 32; ++m) acc[m] = b1s[colbase + m];

    for (int kk = 0; kk < NF; ++kk) {
        float bx = Bs[kk * 3 + 0], by = Bs[kk * 3 + 1], bz = Bs[kk * 3 + 2];
        float f0 = xv[0] * bx + xv[1] * by + xv[2] * bz;
        float f1 = xv[3] * bx + xv[4] * by + xv[5] * bz;
        // sin(2*pi*f) = v_sin(fract(f)) (hardware sin takes revolutions)
        float s0 = __builtin_amdgcn_sinf(__builtin_amdgcn_fractf(f0));
        float c0 = __builtin_amdgcn_cosf(__builtin_amdgcn_fractf(f0));
        float s1 = __builtin_amdgcn_sinf(__builtin_amdgcn_fractf(f1));
        float c1 = __builtin_amdgcn_cosf(__builtin_amdgcn_fractf(f1));
        const float4* r0 = (const float4*)(W1s + (kk           ) * HDIM + colbase);
        const float4* r1 = (const float4*)(W1s + (NF     + kk  ) * HDIM + colbase);
        const float4* r2 = (const float4*)(W1s + (2 * NF + kk  ) * HDIM + colbase);
        const float4* r3 = (const float4*)(W1s + (3 * NF + kk  ) * HDIM + colbase);
        #pragma unroll
        for (int m = 0; m < 8; ++m) {
            float4 a0 = r0[m], a1 = r1[m], a2 = r2[m], a3 = r3[m];
            acc[4 * m + 0] += s0 * a0.x + c0 * a1.x + s1 * a2.x + c1 * a3.x;
            acc[4 * m + 1] += s0 * a0.y + c0 * a1.y + s1 * a2.y + c1 * a3.y;
            acc[4 * m + 2] += s0 * a0.z + c0 * a1.z + s1 * a2.z + c1 * a3.z;
            acc[4 * m + 3] += s0 * a0.w + c0 * a1.w + s1 * a2.w + c1 * a3.w;
        }
    }
    #pragma unroll
    for (int m = 0; m < 32; ++m) lds_h[colbase + m][p] = fast_tanh(acc[m]);
    __syncthreads();

    const float* W2s = W2 + s * (HDIM * HDIM);   // [k][j] row-major
    const float* b2s = b2 + s * HDIM;
    float acc2[32];
    #pragma unroll
    for (int m = 0; m < 32; ++m) acc2[m] = b2s[colbase + m];

    for (int k = 0; k < HDIM; ++k) {
        float hk = lds_h[k][p];
        const float4* r = (const float4*)(W2s + k * HDIM + colbase);
        #pragma unroll
        for (int m = 0; m < 8; ++m) {
            float4 a = r[m];
            acc2[4 * m + 0] += hk * a.x;
            acc2[4 * m + 1] += hk * a.y;
            acc2[4 * m + 2] += hk * a.z;
            acc2[4 * m + 3] += hk * a.w;
        }
    }

    const float* W3s = W3 + s * HDIM;
    float part = 0.0f;
    #pragma unroll
    for (int m = 0; m < 32; ++m)
        part += fast_tanh(acc2[m]) * W3s[colbase + m];
    lds_r[w][p] = part;
    __syncthreads();

    if (threadIdx.x < 64) {
        float tau = b3[s] + lds_r[0][p] + lds_r[1][p] + lds_r[2][p] + lds_r[3][p];
        if (valid) tau_all[s * NPTS + n] = tau;
    }
}

__global__ void finalize(const float* __restrict__ x,
                         const float* __restrict__ mids,
                         const float* __restrict__ widths,
                         const float* __restrict__ tau_all,
                         float* __restrict__ out) {
    int n = blockIdx.x * 256 + threadIdx.x;
    if (n >= NPTS) return;
    float xc = x[n * 6];
    float num = 0.0f, den = 0.0f;
    #pragma unroll
    for (int s = 0; s < NSLAB; ++s) {
        float xmin = mids[s] - 0.5f * widths[s];
        float xmax = mids[s] + 0.5f * widths[s];
        if (xc >= xmin && xc <= xmax) {
            float xs = 2.0f * (xc - xmin) / (xmax - xmin) - 1.0f;
            // cos(pi*xs) = v_cos(fract(xs/2))
            float w = 0.5f * (1.0f + __builtin_amdgcn_cosf(__builtin_amdgcn_fractf(0.5f * xs)));
            num += w * tau_all[s * NPTS + n];
            den += w;
        }
    }
    out[n] = num / den;
}

extern "C" void kernel_launch(void* const* d_in, const int* in_sizes, int n_in,
                              void* d_out, int out_size, void* d_ws, size_t ws_size,
                              hipStream_t stream) {
    const float* x      = (const float*)d_in[0];
    const float* B      = (const float*)d_in[1];
    const float* W1     = (const float*)d_in[2];
    const float* b1     = (const float*)d_in[3];
    const float* W2     = (const float*)d_in[4];
    const float* b2     = (const float*)d_in[5];
    const float* W3     = (const float*)d_in[6];
    const float* b3     = (const float*)d_in[7];
    const float* mids   = (const float*)d_in[8];
    const float* widths = (const float*)d_in[9];
    float* out = (float*)d_out;

    char* ws = (char*)d_ws;
    int*            g_count = (int*)(ws + WS_COUNT_OFF);
    unsigned short* lists   = (unsigned short*)(ws + WS_LIST_OFF);
    float*          tau_all = (float*)(ws + WS_TAU_OFF);

    hipMemsetAsync(g_count, 0, NSLAB * sizeof(int), stream);

    build_lists<<<dim3(NPTS / 256), 256, 0, stream>>>(x, mids, widths, g_count, lists);
    mlp_eval<<<dim3(NPTS / PTS_PER_BLK, NSLAB), 256, 0, stream>>>(
        x, B, W1, b1, W2, b2, W3, b3, mids, widths, g_count, lists, tau_all);
    finalize<<<dim3(NPTS / 256), 256, 0, stream>>>(x, mids, widths, tau_all, out);
}

// Round 4
// 120.200 us; speedup vs baseline: 9.4667x; 9.4667x over previous
//
#include <hip/hip_runtime.h>
#include <hip/hip_bf16.h>

#define NPTS 32768
#define NSLAB 16
#define NF 128
#define HDIM 128
#define KDIM 512          // 4*NF
#define PTS_PER_BLK 64

// ---- workspace layout (bytes) ----
// [0, 64)      : g_count[16] (int)
// [1024, +1MB) : lists, u16 [16][NPTS]
// [2MB, 4MB)   : tau_all, f32 [16][NPTS]
// [4MB, 6MB)   : W1T bf16 [16][128][512]
// [6MB, 6.5MB) : W2T bf16 [16][128][128]
#define WS_COUNT_OFF   0
#define WS_LIST_OFF    1024
#define WS_TAU_OFF     (2u << 20)
#define WS_W1T_OFF     (4u << 20)
#define WS_W2T_OFF     (6u << 20)

typedef __attribute__((ext_vector_type(8))) short bf16x8;
typedef __attribute__((ext_vector_type(4))) float f32x4;

__device__ __forceinline__ unsigned short f2bf(float f) {
    union { float f; unsigned u; } v; v.f = f;
    unsigned u = v.u;
    return (unsigned short)((u + 0x7FFFu + ((u >> 16) & 1u)) >> 16);
}
__device__ __forceinline__ float bf2f(unsigned short h) {
    union { unsigned u; float f; } v; v.u = ((unsigned)h) << 16; return v.f;
}
__device__ __forceinline__ float fast_tanh(float v) {
    v = fminf(fmaxf(v, -15.0f), 15.0f);
    float t = __builtin_amdgcn_exp2f(v * 2.8853900817779268f); // e^{2v}
    return (t - 1.0f) * __builtin_amdgcn_rcpf(t + 1.0f);
}

// Transpose + f32->bf16: out[s][n][k] = bf16(in[s][k][n]).  32x32 tiles.
__global__ void conv_transpose(const float* __restrict__ in, unsigned short* __restrict__ out,
                               int K, int N) {
    __shared__ float tl[32][33];
    int tiles_n = N >> 5;
    int tk = blockIdx.x / tiles_n, tn = blockIdx.x % tiles_n;
    int s = blockIdx.y;
    const float* ins = in + (size_t)s * K * N;
    unsigned short* outs = out + (size_t)s * N * K;
    int t = threadIdx.x, r4 = t >> 5, c = t & 31;
    #pragma unroll
    for (int i = 0; i < 4; ++i) {
        int r = i * 8 + r4;
        tl[r][c] = ins[(tk * 32 + r) * N + tn * 32 + c];
    }
    __syncthreads();
    #pragma unroll
    for (int i = 0; i < 4; ++i) {
        int r = i * 8 + r4;
        outs[(size_t)(tn * 32 + r) * K + tk * 32 + c] = f2bf(tl[c][r]);
    }
}

__global__ void build_lists(const float* __restrict__ x,
                            const float* __restrict__ mids,
                            const float* __restrict__ widths,
                            int* __restrict__ g_count,
                            unsigned short* __restrict__ lists) {
    __shared__ int cnt[NSLAB];
    __shared__ int base[NSLAB];
    int tid = threadIdx.x;
    if (tid < NSLAB) cnt[tid] = 0;
    __syncthreads();
    int n = blockIdx.x * 256 + tid;
    float xc = x[n * 6];
    int ofs[NSLAB];
    unsigned int amask = 0;
    #pragma unroll
    for (int s = 0; s < NSLAB; ++s) {
        float xmin = mids[s] - 0.5f * widths[s];
        float xmax = mids[s] + 0.5f * widths[s];
        if (xc >= xmin && xc <= xmax) {
            ofs[s] = atomicAdd(&cnt[s], 1);
            amask |= (1u << s);
        }
    }
    __syncthreads();
    if (tid < NSLAB) base[tid] = atomicAdd(&g_count[tid], cnt[tid]);
    __syncthreads();
    #pragma unroll
    for (int s = 0; s < NSLAB; ++s)
        if (amask & (1u << s))
            lists[s * NPTS + base[s] + ofs[s]] = (unsigned short)n;
}

// Block: 256 thr = 4 waves; 64 points x 1 slab. Wave w owns output cols [32w,32w+32).
// MFMA 16x16x32 bf16. A-frag: lane holds A[l&15][(l>>4)*8+j]. B-frag: B[(l>>4)*8+j][l&15].
// C/D: col=l&15, row=(l>>4)*4+reg.
__global__ __launch_bounds__(256, 4) void mlp_eval(
        const float* __restrict__ x,  const float* __restrict__ B,
        const unsigned short* __restrict__ W1T, const float* __restrict__ b1,
        const unsigned short* __restrict__ W2T, const float* __restrict__ b2,
        const float* __restrict__ W3, const float* __restrict__ b3,
        const float* __restrict__ mids, const float* __restrict__ widths,
        const int* __restrict__ g_count,
        const unsigned short* __restrict__ lists,
        float* __restrict__ tau_all) {
    int s = blockIdx.y;
    int count = g_count[s];
    int pbase = blockIdx.x * PTS_PER_BLK;
    if (count == 0 || pbase >= count) return;

    __shared__ short feat[PTS_PER_BLK * 64];    // 8KB, swizzled, per K-chunk
    __shared__ short hbuf[PTS_PER_BLK * HDIM];  // 16KB, swizzled (h1 then h2)
    __shared__ float xp[PTS_PER_BLK][6];
    __shared__ int   ns[PTS_PER_BLK];
    __shared__ float lds_r[4][PTS_PER_BLK];

    int t = threadIdx.x;
    int w = t >> 6;          // wave id = output col block = layer3 col group
    int l = t & 63;          // lane
    int lrow = l & 15;
    int khi = l >> 4;        // 0..3

    float mid = mids[s], wd = widths[s];
    if (t < PTS_PER_BLK) {
        int idx = pbase + t;
        int ii = idx < count ? idx : count - 1;
        int n = lists[s * NPTS + ii];
        ns[t] = n;
        const float* xr = x + n * 6;
        #pragma unroll
        for (int d = 0; d < 6; ++d) xp[t][d] = (xr[d] - mid) / wd;
    }
    __syncthreads();

    const float* Bs   = B   + s * (NF * 3);
    const unsigned short* W1Ts = W1T + (size_t)s * HDIM * KDIM;
    const unsigned short* W2Ts = W2T + (size_t)s * HDIM * HDIM;
    const float* b1s = b1 + s * HDIM;
    const float* b2s = b2 + s * HDIM;
    const float* W3s = W3 + s * HDIM;

    // ---- layer 1: feat[64x512] * W1[512x128] ----
    f32x4 acc1[4][2];
    #pragma unroll
    for (int mt = 0; mt < 4; ++mt)
        #pragma unroll
        for (int nt = 0; nt < 2; ++nt) {
            float bv = b1s[w * 32 + nt * 16 + lrow];
            acc1[mt][nt] = (f32x4){bv, bv, bv, bv};
        }

    int fp = t >> 2;         // point this thread fills feat for
    int fg = t & 3;          // k-subgroup of 16
    for (int c = 0; c < 8; ++c) {            // K-chunks of 64
        __syncthreads();                      // prior chunk's reads done
        // fill feat chunk: cols k = c*64 .. c*64+63
        int type = c >> 1;                    // 0:sinF0 1:cosF0 2:sinF1 3:cosF1
        int fbase = (c & 1) * 64 + fg * 16;   // frequency index base
        float x0 = xp[fp][type >= 2 ? 3 : 0];
        float x1 = xp[fp][type >= 2 ? 4 : 1];
        float x2 = xp[fp][type >= 2 ? 5 : 2];
        bool use_cos = (type & 1);
        bf16x8 fva, fvb;
        #pragma unroll
        for (int j = 0; j < 16; ++j) {
            const float* br = Bs + (fbase + j) * 3;
            float F = x0 * br[0] + x1 * br[1] + x2 * br[2];
            float ph = __builtin_amdgcn_fractf(F);
            float v = use_cos ? __builtin_amdgcn_cosf(ph) : __builtin_amdgcn_sinf(ph);
            if (j < 8) fva[j] = (short)f2bf(v); else fvb[j - 8] = (short)f2bf(v);
        }
        {
            unsigned swz = (unsigned)((fp & 7) << 4);
            unsigned ba = (unsigned)(fp * 128 + fg * 32) ^ swz;
            unsigned bb = (unsigned)(fp * 128 + fg * 32 + 16) ^ swz;
            *(bf16x8*)((char*)feat + ba) = fva;
            *(bf16x8*)((char*)feat + bb) = fvb;
        }
        __syncthreads();
        // MFMA over this chunk: 2 k-steps of 32
        #pragma unroll
        for (int ks = 0; ks < 2; ++ks) {
            bf16x8 af[4];
            #pragma unroll
            for (int mt = 0; mt < 4; ++mt) {
                int row = mt * 16 + lrow;
                unsigned byte = (unsigned)(row * 128 + ks * 64 + khi * 16) ^ ((unsigned)(row & 7) << 4);
                af[mt] = *(const bf16x8*)((const char*)feat + byte);
            }
            bf16x8 bfr[2];
            #pragma unroll
            for (int nt = 0; nt < 2; ++nt) {
                int n = w * 32 + nt * 16 + lrow;
                int k = c * 64 + ks * 32 + khi * 8;
                bfr[nt] = *(const bf16x8*)(W1Ts + (size_t)n * KDIM + k);
            }
            #pragma unroll
            for (int mt = 0; mt < 4; ++mt)
                #pragma unroll
                for (int nt = 0; nt < 2; ++nt)
                    acc1[mt][nt] = __builtin_amdgcn_mfma_f32_16x16x32_bf16(
                        af[mt], bfr[nt], acc1[mt][nt], 0, 0, 0);
        }
    }
    __syncthreads();
    // tanh -> bf16 -> hbuf (swizzled [point][col], stride 256B)
    #pragma unroll
    for (int mt = 0; mt < 4; ++mt)
        #pragma unroll
        for (int nt = 0; nt < 2; ++nt)
            #pragma unroll
            for (int r = 0; r < 4; ++r) {
                int row = mt * 16 + khi * 4 + r;
                int col = w * 32 + nt * 16 + lrow;
                unsigned byte = (unsigned)(row * 256 + col * 2) ^ ((unsigned)(row & 7) << 4);
                *(short*)((char*)hbuf + byte) = (short)f2bf(fast_tanh(acc1[mt][nt][r]));
            }
    __syncthreads();

    // ---- layer 2: h1[64x128] * W2[128x128] ----
    f32x4 acc2[4][2];
    #pragma unroll
    for (int mt = 0; mt < 4; ++mt)
        #pragma unroll
        for (int nt = 0; nt < 2; ++nt) {
            float bv = b2s[w * 32 + nt * 16 + lrow];
            acc2[mt][nt] = (f32x4){bv, bv, bv, bv};
        }
    #pragma unroll
    for (int ks = 0; ks < 4; ++ks) {
        bf16x8 af[4];
        #pragma unroll
        for (int mt = 0; mt < 4; ++mt) {
            int row = mt * 16 + lrow;
            unsigned byte = (unsigned)(row * 256 + ks * 64 + khi * 16) ^ ((unsigned)(row & 7) << 4);
            af[mt] = *(const bf16x8*)((const char*)hbuf + byte);
        }
        bf16x8 bfr[2];
        #pragma unroll
        for (int nt = 0; nt < 2; ++nt) {
            int n = w * 32 + nt * 16 + lrow;
            bfr[nt] = *(const bf16x8*)(W2Ts + (size_t)n * HDIM + ks * 32 + khi * 8);
        }
        #pragma unroll
        for (int mt = 0; mt < 4; ++mt)
            #pragma unroll
            for (int nt = 0; nt < 2; ++nt)
                acc2[mt][nt] = __builtin_amdgcn_mfma_f32_16x16x32_bf16(
                    af[mt], bfr[nt], acc2[mt][nt], 0, 0, 0);
    }
    __syncthreads();   // all hbuf(h1) reads done
    #pragma unroll
    for (int mt = 0; mt < 4; ++mt)
        #pragma unroll
        for (int nt = 0; nt < 2; ++nt)
            #pragma unroll
            for (int r = 0; r < 4; ++r) {
                int row = mt * 16 + khi * 4 + r;
                int col = w * 32 + nt * 16 + lrow;
                unsigned byte = (unsigned)(row * 256 + col * 2) ^ ((unsigned)(row & 7) << 4);
                *(short*)((char*)hbuf + byte) = (short)f2bf(fast_tanh(acc2[mt][nt][r]));
            }
    __syncthreads();

    // ---- layer 3: h2[64x128] * W3[128] ; wave w does cols [32w,32w+32) for point=lane ----
    float part = 0.0f;
    #pragma unroll
    for (int u = 0; u < 4; ++u) {
        int cb = w * 32 + u * 8;
        unsigned byte = (unsigned)(l * 256 + cb * 2) ^ ((unsigned)(l & 7) << 4);
        bf16x8 hv = *(const bf16x8*)((const char*)hbuf + byte);
        #pragma unroll
        for (int e = 0; e < 8; ++e)
            part += bf2f((unsigned short)hv[e]) * W3s[cb + e];
    }
    lds_r[w][l] = part;
    __syncthreads();
    if (t < PTS_PER_BLK) {
        float tau = b3[s] + lds_r[0][t] + lds_r[1][t] + lds_r[2][t] + lds_r[3][t];
        if (pbase + t < count) tau_all[s * NPTS + ns[t]] = tau;
    }
}

__global__ void finalize(const float* __restrict__ x,
                         const float* __restrict__ mids,
                         const float* __restrict__ widths,
                         const float* __restrict__ tau_all,
                         float* __restrict__ out) {
    int n = blockIdx.x * 256 + threadIdx.x;
    if (n >= NPTS) return;
    float xc = x[n * 6];
    float num = 0.0f, den = 0.0f;
    #pragma unroll
    for (int s = 0; s < NSLAB; ++s) {
        float xmin = mids[s] - 0.5f * widths[s];
        float xmax = mids[s] + 0.5f * widths[s];
        if (xc >= xmin && xc <= xmax) {
            float xs = 2.0f * (xc - xmin) / (xmax - xmin) - 1.0f;
            float w = 0.5f * (1.0f + __builtin_amdgcn_cosf(__builtin_amdgcn_fractf(0.5f * xs)));
            num += w * tau_all[s * NPTS + n];
            den += w;
        }
    }
    out[n] = num / den;
}

extern "C" void kernel_launch(void* const* d_in, const int* in_sizes, int n_in,
                              void* d_out, int out_size, void* d_ws, size_t ws_size,
                              hipStream_t stream) {
    const float* x      = (const float*)d_in[0];
    const float* B      = (const float*)d_in[1];
    const float* W1     = (const float*)d_in[2];
    const float* b1     = (const float*)d_in[3];
    const float* W2     = (const float*)d_in[4];
    const float* b2     = (const float*)d_in[5];
    const float* W3     = (const float*)d_in[6];
    const float* b3     = (const float*)d_in[7];
    const float* mids   = (const float*)d_in[8];
    const float* widths = (const float*)d_in[9];
    float* out = (float*)d_out;

    char* ws = (char*)d_ws;
    int*            g_count = (int*)(ws + WS_COUNT_OFF);
    unsigned short* lists   = (unsigned short*)(ws + WS_LIST_OFF);
    float*          tau_all = (float*)(ws + WS_TAU_OFF);
    unsigned short* W1T     = (unsigned short*)(ws + WS_W1T_OFF);
    unsigned short* W2T     = (unsigned short*)(ws + WS_W2T_OFF);

    (void)hipMemsetAsync(g_count, 0, NSLAB * sizeof(int), stream);

    conv_transpose<<<dim3((KDIM / 32) * (HDIM / 32), NSLAB), 256, 0, stream>>>(W1, W1T, KDIM, HDIM);
    conv_transpose<<<dim3((HDIM / 32) * (HDIM / 32), NSLAB), 256, 0, stream>>>(W2, W2T, HDIM, HDIM);
    build_lists<<<dim3(NPTS / 256), 256, 0, stream>>>(x, mids, widths, g_count, lists);
    mlp_eval<<<dim3(128, NSLAB), 256, 0, stream>>>(
        x, B, W1T, b1, W2T, b2, W3, b3, mids, widths, g_count, lists, tau_all);
    finalize<<<dim3(NPTS / 256), 256, 0, stream>>>(x, mids, widths, tau_all, out);
}

// Round 5
// 75.691 us; speedup vs baseline: 15.0333x; 1.5880x over previous
//
#include <hip/hip_runtime.h>
#include <hip/hip_bf16.h>

#define NPTS 32768
#define NSLAB 16
#define NF 128
#define HDIM 128
#define KDIM 512          // 4*NF
#define PTS_PER_BLK 64

// ---- workspace layout (bytes) ----
// [0, 64)      : g_count[16] (int)
// [1024, +1MB) : lists, u16 [16][NPTS]
// [2MB, 4MB)   : tau_all, f32 [16][NPTS]
// [4MB, 6MB)   : W1T bf16 [16][128][512]  (K-permuted: k' = f*4+type)
// [6MB, 6.5MB) : W2T bf16 [16][128][128]
#define WS_COUNT_OFF   0
#define WS_LIST_OFF    1024
#define WS_TAU_OFF     (2u << 20)
#define WS_W1T_OFF     (4u << 20)
#define WS_W2T_OFF     (6u << 20)

typedef __attribute__((ext_vector_type(8))) short bf16x8;
typedef __attribute__((ext_vector_type(4))) float f32x4;
typedef __attribute__((ext_vector_type(4))) unsigned int u32x4;

__device__ __forceinline__ unsigned short f2bf(float f) {
    union { float f; unsigned u; } v; v.f = f;
    unsigned u = v.u;
    return (unsigned short)((u + 0x7FFFu + ((u >> 16) & 1u)) >> 16);
}
__device__ __forceinline__ float bf2f(unsigned short h) {
    union { unsigned u; float f; } v; v.u = ((unsigned)h) << 16; return v.f;
}
__device__ __forceinline__ float fast_tanh(float v) {
    v = fminf(fmaxf(v, -15.0f), 15.0f);
    float t = __builtin_amdgcn_exp2f(v * 2.8853900817779268f); // e^{2v}
    return (t - 1.0f) * __builtin_amdgcn_rcpf(t + 1.0f);
}
// pack two f32 -> one u32 of two bf16 (lo = a, hi = b)
__device__ __forceinline__ unsigned pk_bf16(float a, float b) {
    unsigned r;
    asm("v_cvt_pk_bf16_f32 %0, %1, %2" : "=v"(r) : "v"(a), "v"(b));
    return r;
}

// Transpose + f32->bf16: out[s][n][perm(k)] = bf16(in[s][k][n]).  32x32 tiles.
__global__ void conv_transpose(const float* __restrict__ in, unsigned short* __restrict__ out,
                               int K, int N, int perm) {
    __shared__ float tl[32][33];
    int tiles_n = N >> 5;
    int tk = blockIdx.x / tiles_n, tn = blockIdx.x % tiles_n;
    int s = blockIdx.y;
    const float* ins = in + (size_t)s * K * N;
    unsigned short* outs = out + (size_t)s * N * K;
    int t = threadIdx.x, r4 = t >> 5, c = t & 31;
    #pragma unroll
    for (int i = 0; i < 4; ++i) {
        int r = i * 8 + r4;
        tl[r][c] = ins[(tk * 32 + r) * N + tn * 32 + c];
    }
    __syncthreads();
    #pragma unroll
    for (int i = 0; i < 4; ++i) {
        int r = i * 8 + r4;
        int k = tk * 32 + c;
        int kp = perm ? ((k & 127) * 4 + (k >> 7)) : k;
        outs[(size_t)(tn * 32 + r) * K + kp] = f2bf(tl[c][r]);
    }
}

__global__ void build_lists(const float* __restrict__ x,
                            const float* __restrict__ mids,
                            const float* __restrict__ widths,
                            int* __restrict__ g_count,
                            unsigned short* __restrict__ lists) {
    __shared__ int cnt[NSLAB];
    __shared__ int base[NSLAB];
    int tid = threadIdx.x;
    if (tid < NSLAB) cnt[tid] = 0;
    __syncthreads();
    int n = blockIdx.x * 256 + tid;
    float xc = x[n * 6];
    int ofs[NSLAB];
    unsigned int amask = 0;
    #pragma unroll
    for (int s = 0; s < NSLAB; ++s) {
        float xmin = mids[s] - 0.5f * widths[s];
        float xmax = mids[s] + 0.5f * widths[s];
        if (xc >= xmin && xc <= xmax) {
            ofs[s] = atomicAdd(&cnt[s], 1);
            amask |= (1u << s);
        }
    }
    __syncthreads();
    if (tid < NSLAB) base[tid] = atomicAdd(&g_count[tid], cnt[tid]);
    __syncthreads();
    #pragma unroll
    for (int s = 0; s < NSLAB; ++s)
        if (amask & (1u << s))
            lists[s * NPTS + base[s] + ofs[s]] = (unsigned short)n;
}

// Block: 256 thr = 4 waves; 64 points x 1 slab. Wave w owns output cols [32w,32w+32).
// MFMA 16x16x32 bf16. A-frag: lane holds A[l&15][(l>>4)*8+j]. B-frag: B[(l>>4)*8+j][l&15].
// C/D: col=l&15, row=(l>>4)*4+reg.
__global__ __launch_bounds__(256, 4) void mlp_eval(
        const float* __restrict__ x,  const float* __restrict__ B,
        const unsigned short* __restrict__ W1T, const float* __restrict__ b1,
        const unsigned short* __restrict__ W2T, const float* __restrict__ b2,
        const float* __restrict__ W3, const float* __restrict__ b3,
        const float* __restrict__ mids, const float* __restrict__ widths,
        const int* __restrict__ g_count,
        const unsigned short* __restrict__ lists,
        float* __restrict__ tau_all) {
    int s = blockIdx.y;
    int count = g_count[s];
    int pbase = blockIdx.x * PTS_PER_BLK;
    if (count == 0 || pbase >= count) return;

    // smem: double-buffered feat (2 x 64x64 bf16 = 16KB), later overlaid by hbuf (64x128 bf16 = 16KB)
    __shared__ short smem[8192];
    __shared__ float lds_B[NF * 3];           // 1.5KB  B rows [f][3]
    __shared__ float xp[PTS_PER_BLK][6];
    __shared__ int   ns[PTS_PER_BLK];
    __shared__ float lds_r[4][PTS_PER_BLK];

    int t = threadIdx.x;
    int w = t >> 6;          // wave id = output col block
    int l = t & 63;          // lane
    int lrow = l & 15;
    int khi = l >> 4;        // 0..3

    float mid = mids[s], wd = widths[s];
    if (t < PTS_PER_BLK) {
        int idx = pbase + t;
        int ii = idx < count ? idx : count - 1;
        int n = lists[s * NPTS + ii];
        ns[t] = n;
        const float* xr = x + n * 6;
        #pragma unroll
        for (int d = 0; d < 6; ++d) xp[t][d] = (xr[d] - mid) / wd;
    }
    // stage B slab into LDS (128*3 floats = 96 float4)
    if (t < 96) ((f32x4*)lds_B)[t] = ((const f32x4*)(B + s * (NF * 3)))[t];
    __syncthreads();

    const unsigned short* W1Ts = W1T + (size_t)s * HDIM * KDIM;
    const unsigned short* W2Ts = W2T + (size_t)s * HDIM * HDIM;
    const float* b1s = b1 + s * HDIM;
    const float* b2s = b2 + s * HDIM;
    const float* W3s = W3 + s * HDIM;

    int p = t >> 2;          // point this thread fills feat for
    int g = t & 3;           // freq subgroup (4 freqs per thread per chunk)
    float xv0 = xp[p][0], xv1 = xp[p][1], xv2 = xp[p][2];
    float xv3 = xp[p][3], xv4 = xp[p][4], xv5 = xp[p][5];
    unsigned wbyte0 = ((unsigned)(p * 128 + g * 32)) ^ ((unsigned)(p & 7) << 4);
    unsigned wbyte1 = ((unsigned)(p * 128 + g * 32 + 16)) ^ ((unsigned)(p & 7) << 4);

    // ---- layer 1: feat[64x512] * W1[512x128], K interleaved (f*4+type) ----
    f32x4 acc1[4][2];
    #pragma unroll
    for (int mt = 0; mt < 4; ++mt)
        #pragma unroll
        for (int nt = 0; nt < 2; ++nt) {
            float bv = b1s[w * 32 + nt * 16 + lrow];
            acc1[mt][nt] = (f32x4){bv, bv, bv, bv};
        }

    // feat fill for chunk c into buffer (c&1): freqs [16c, 16c+16), this thread does 4
    #define FILL_CHUNK(c)                                                          \
    do {                                                                           \
        short* fb = smem + ((c) & 1) * 4096;                                       \
        const f32x4* bq = (const f32x4*)lds_B + (12 * (c) + 3 * g);                \
        f32x4 q0 = bq[0], q1 = bq[1], q2 = bq[2];                                  \
        float bf_[12] = {q0.x, q0.y, q0.z, q0.w, q1.x, q1.y, q1.z, q1.w,           \
                         q2.x, q2.y, q2.z, q2.w};                                  \
        unsigned pk[8];                                                            \
        _Pragma("unroll")                                                          \
        for (int jf = 0; jf < 4; ++jf) {                                           \
            float b0 = bf_[jf * 3], b1v = bf_[jf * 3 + 1], b2v = bf_[jf * 3 + 2];  \
            float F0 = xv0 * b0 + xv1 * b1v + xv2 * b2v;                           \
            float F1 = xv3 * b0 + xv4 * b1v + xv5 * b2v;                           \
            float p0 = __builtin_amdgcn_fractf(F0);                                \
            float p1 = __builtin_amdgcn_fractf(F1);                                \
            float s0 = __builtin_amdgcn_sinf(p0), c0 = __builtin_amdgcn_cosf(p0);  \
            float s1 = __builtin_amdgcn_sinf(p1), c1 = __builtin_amdgcn_cosf(p1);  \
            pk[jf * 2]     = pk_bf16(s0, c0);                                      \
            pk[jf * 2 + 1] = pk_bf16(s1, c1);                                      \
        }                                                                          \
        *(u32x4*)((char*)fb + wbyte0) = (u32x4){pk[0], pk[1], pk[2], pk[3]};       \
        *(u32x4*)((char*)fb + wbyte1) = (u32x4){pk[4], pk[5], pk[6], pk[7]};       \
    } while (0)

    FILL_CHUNK(0);
    __syncthreads();
    for (int c = 0; c < 8; ++c) {
        // issue W1T B-fragment loads for this chunk first (L2 latency hides under fill)
        bf16x8 bfr[2][2];
        #pragma unroll
        for (int ks = 0; ks < 2; ++ks)
            #pragma unroll
            for (int nt = 0; nt < 2; ++nt) {
                int n = w * 32 + nt * 16 + lrow;
                int k = c * 64 + ks * 32 + khi * 8;
                bfr[ks][nt] = *(const bf16x8*)(W1Ts + (size_t)n * KDIM + k);
            }
        if (c < 7) FILL_CHUNK(c + 1);
        const short* fb = smem + (c & 1) * 4096;
        #pragma unroll
        for (int ks = 0; ks < 2; ++ks) {
            bf16x8 af[4];
            #pragma unroll
            for (int mt = 0; mt < 4; ++mt) {
                int row = mt * 16 + lrow;
                unsigned byte = (unsigned)(row * 128 + ks * 64 + khi * 16) ^ ((unsigned)(row & 7) << 4);
                af[mt] = *(const bf16x8*)((const char*)fb + byte);
            }
            #pragma unroll
            for (int mt = 0; mt < 4; ++mt)
                #pragma unroll
                for (int nt = 0; nt < 2; ++nt)
                    acc1[mt][nt] = __builtin_amdgcn_mfma_f32_16x16x32_bf16(
                        af[mt], bfr[ks][nt], acc1[mt][nt], 0, 0, 0);
        }
        __syncthreads();
    }

    // tanh -> bf16 -> hbuf (overlays feat; swizzled [point][col], row stride 256B)
    short* hbuf = smem;
    #pragma unroll
    for (int mt = 0; mt < 4; ++mt)
        #pragma unroll
        for (int nt = 0; nt < 2; ++nt)
            #pragma unroll
            for (int r = 0; r < 4; ++r) {
                int row = mt * 16 + khi * 4 + r;
                int col = w * 32 + nt * 16 + lrow;
                unsigned byte = (unsigned)(row * 256 + col * 2) ^ ((unsigned)(row & 7) << 4);
                *(short*)((char*)hbuf + byte) = (short)f2bf(fast_tanh(acc1[mt][nt][r]));
            }
    __syncthreads();

    // ---- layer 2: h1[64x128] * W2[128x128] ----
    f32x4 acc2[4][2];
    #pragma unroll
    for (int mt = 0; mt < 4; ++mt)
        #pragma unroll
        for (int nt = 0; nt < 2; ++nt) {
            float bv = b2s[w * 32 + nt * 16 + lrow];
            acc2[mt][nt] = (f32x4){bv, bv, bv, bv};
        }
    #pragma unroll
    for (int ks = 0; ks < 4; ++ks) {
        bf16x8 af[4];
        #pragma unroll
        for (int mt = 0; mt < 4; ++mt) {
            int row = mt * 16 + lrow;
            unsigned byte = (unsigned)(row * 256 + ks * 64 + khi * 16) ^ ((unsigned)(row & 7) << 4);
            af[mt] = *(const bf16x8*)((const char*)hbuf + byte);
        }
        bf16x8 bfr[2];
        #pragma unroll
        for (int nt = 0; nt < 2; ++nt) {
            int n = w * 32 + nt * 16 + lrow;
            bfr[nt] = *(const bf16x8*)(W2Ts + (size_t)n * HDIM + ks * 32 + khi * 8);
        }
        #pragma unroll
        for (int mt = 0; mt < 4; ++mt)
            #pragma unroll
            for (int nt = 0; nt < 2; ++nt)
                acc2[mt][nt] = __builtin_amdgcn_mfma_f32_16x16x32_bf16(
                    af[mt], bfr[nt], acc2[mt][nt], 0, 0, 0);
    }
    __syncthreads();   // all hbuf(h1) reads done
    #pragma unroll
    for (int mt = 0; mt < 4; ++mt)
        #pragma unroll
        for (int nt = 0; nt < 2; ++nt)
            #pragma unroll
            for (int r = 0; r < 4; ++r) {
                int row = mt * 16 + khi * 4 + r;
                int col = w * 32 + nt * 16 + lrow;
                unsigned byte = (unsigned)(row * 256 + col * 2) ^ ((unsigned)(row & 7) << 4);
                *(short*)((char*)hbuf + byte) = (short)f2bf(fast_tanh(acc2[mt][nt][r]));
            }
    __syncthreads();

    // ---- layer 3: h2[64x128] * W3[128] ----
    float part = 0.0f;
    #pragma unroll
    for (int u = 0; u < 4; ++u) {
        int cb = w * 32 + u * 8;
        unsigned byte = (unsigned)(l * 256 + cb * 2) ^ ((unsigned)(l & 7) << 4);
        bf16x8 hv = *(const bf16x8*)((const char*)hbuf + byte);
        #pragma unroll
        for (int e = 0; e < 8; ++e)
            part += bf2f((unsigned short)hv[e]) * W3s[cb + e];
    }
    lds_r[w][l] = part;
    __syncthreads();
    if (t < PTS_PER_BLK) {
        float tau = b3[s] + lds_r[0][t] + lds_r[1][t] + lds_r[2][t] + lds_r[3][t];
        if (pbase + t < count) tau_all[s * NPTS + ns[t]] = tau;
    }
}

__global__ void finalize(const float* __restrict__ x,
                         const float* __restrict__ mids,
                         const float* __restrict__ widths,
                         const float* __restrict__ tau_all,
                         float* __restrict__ out) {
    int n = blockIdx.x * 256 + threadIdx.x;
    if (n >= NPTS) return;
    float xc = x[n * 6];
    float num = 0.0f, den = 0.0f;
    #pragma unroll
    for (int s = 0; s < NSLAB; ++s) {
        float xmin = mids[s] - 0.5f * widths[s];
        float xmax = mids[s] + 0.5f * widths[s];
        if (xc >= xmin && xc <= xmax) {
            float xs = 2.0f * (xc - xmin) / (xmax - xmin) - 1.0f;
            float w = 0.5f * (1.0f + __builtin_amdgcn_cosf(__builtin_amdgcn_fractf(0.5f * xs)));
            num += w * tau_all[s * NPTS + n];
            den += w;
        }
    }
    out[n] = num / den;
}

extern "C" void kernel_launch(void* const* d_in, const int* in_sizes, int n_in,
                              void* d_out, int out_size, void* d_ws, size_t ws_size,
                              hipStream_t stream) {
    const float* x      = (const float*)d_in[0];
    const float* B      = (const float*)d_in[1];
    const float* W1     = (const float*)d_in[2];
    const float* b1     = (const float*)d_in[3];
    const float* W2     = (const float*)d_in[4];
    const float* b2     = (const float*)d_in[5];
    const float* W3     = (const float*)d_in[6];
    const float* b3     = (const float*)d_in[7];
    const float* mids   = (const float*)d_in[8];
    const float* widths = (const float*)d_in[9];
    float* out = (float*)d_out;

    char* ws = (char*)d_ws;
    int*            g_count = (int*)(ws + WS_COUNT_OFF);
    unsigned short* lists   = (unsigned short*)(ws + WS_LIST_OFF);
    float*          tau_all = (float*)(ws + WS_TAU_OFF);
    unsigned short* W1T     = (unsigned short*)(ws + WS_W1T_OFF);
    unsigned short* W2T     = (unsigned short*)(ws + WS_W2T_OFF);

    (void)hipMemsetAsync(g_count, 0, NSLAB * sizeof(int), stream);

    conv_transpose<<<dim3((KDIM / 32) * (HDIM / 32), NSLAB), 256, 0, stream>>>(W1, W1T, KDIM, HDIM, 1);
    conv_transpose<<<dim3((HDIM / 32) * (HDIM / 32), NSLAB), 256, 0, stream>>>(W2, W2T, HDIM, HDIM, 0);
    build_lists<<<dim3(NPTS / 256), 256, 0, stream>>>(x, mids, widths, g_count, lists);
    mlp_eval<<<dim3(128, NSLAB), 256, 0, stream>>>(
        x, B, W1T, b1, W2T, b2, W3, b3, mids, widths, g_count, lists, tau_all);
    finalize<<<dim3(NPTS / 256), 256, 0, stream>>>(x, mids, widths, tau_all, out);
}